// Round 1
// baseline (337.187 us; speedup 1.0000x reference)
//
#include <hip/hip_runtime.h>
#include <hip/hip_bf16.h>
#include <math.h>

#define D_MODEL 1024
#define D_HIDDEN 4096
#define N_EXP 8
#define N_TOK 4096

typedef __attribute__((ext_vector_type(8))) __bf16 bf16x8_t;
typedef __attribute__((ext_vector_type(4))) float f32x4_t;

// ---- workspace layout (bytes) ----
// counts : 8 ints                     @ 0
// bucket : 8*4096 ints (128 KiB)     @ 256
// xb     : 4096*1024 bf16 (8 MiB)    @ 256 KiB
// h      : 4096*4096 bf16 (32 MiB)   @ 256 KiB + 8 MiB
#define WS_BUCKET_OFF 256
#define WS_XB_OFF     (1u << 18)
#define WS_H_OFF      ((1u << 18) + (8u << 20))

__device__ __forceinline__ void gload16(const void* g, void* l) {
    __builtin_amdgcn_global_load_lds(
        (__attribute__((address_space(1))) void*)(g),
        (__attribute__((address_space(3))) void*)(l),
        16, 0, 0);
}

__global__ __launch_bounds__(64) void init_counts(int* counts) {
    if (threadIdx.x < N_EXP) counts[threadIdx.x] = 0;
}

// Router: one wave per token. fp64 accumulation for logits (argmax robustness),
// also converts x row to bf16 (coalesced 2B stores).
__global__ __launch_bounds__(256) void router_kernel(
    const float* __restrict__ x, const float* __restrict__ Wg,
    const float* __restrict__ bg, int* __restrict__ counts,
    int* __restrict__ bucket, __hip_bfloat16* __restrict__ xb)
{
    const int wid  = threadIdx.x >> 6;
    const int lane = threadIdx.x & 63;
    const int t    = blockIdx.x * 4 + wid;
    const float* xr = x + (size_t)t * D_MODEL;

    double acc[N_EXP];
#pragma unroll
    for (int e = 0; e < N_EXP; ++e) acc[e] = 0.0;

#pragma unroll
    for (int j = 0; j < D_MODEL / 64; ++j) {
        const int d = j * 64 + lane;
        const float xv = xr[d];
        xb[(size_t)t * D_MODEL + d] = __float2bfloat16(xv);
        const float4* wr = (const float4*)(Wg + (size_t)d * N_EXP);
        const float4 w0 = wr[0], w1 = wr[1];
        const double xd = (double)xv;
        acc[0] += xd * (double)w0.x; acc[1] += xd * (double)w0.y;
        acc[2] += xd * (double)w0.z; acc[3] += xd * (double)w0.w;
        acc[4] += xd * (double)w1.x; acc[5] += xd * (double)w1.y;
        acc[6] += xd * (double)w1.z; acc[7] += xd * (double)w1.w;
    }
#pragma unroll
    for (int e = 0; e < N_EXP; ++e) {
        double v = acc[e];
#pragma unroll
        for (int off = 32; off >= 1; off >>= 1) v += __shfl_xor(v, off, 64);
        acc[e] = v + (double)bg[e];
    }
    if (lane == 0) {
        int best = 0; double bv = acc[0];
#pragma unroll
        for (int e = 1; e < N_EXP; ++e)
            if (acc[e] > bv) { bv = acc[e]; best = e; }   // strict > : first max wins (np argmax)
        const int pos = atomicAdd(&counts[best], 1);
        bucket[best * N_TOK + pos] = t;
    }
}

// Grouped GEMM over one expert's token bucket.
// A: [N_TOK][K_TOT] bf16 (gathered rows by token id)
// W: [E][K_TOT][N_TOT] fp32 (converted to bf16 during staging)
// Tile 64x64x64, 4 waves, each wave 32x32 via 2x2 of 16x16x32 MFMA.
// LDS layout XOR-swizzled: phys 16B slot = logical slot ^ (row&7).
template<int K_TOT, int N_TOT, bool IS_FFN1>
__global__ __launch_bounds__(256) void ffn_gemm(
    const __hip_bfloat16* __restrict__ A,
    const float* __restrict__ W,
    const float* __restrict__ bias,
    const int* __restrict__ counts,
    const int* __restrict__ bucket,
    __hip_bfloat16* __restrict__ hout,
    float* __restrict__ yout)
{
    const int e   = blockIdx.z;
    const int cnt = counts[e];
    const int m0  = blockIdx.y * 64;
    if (m0 >= cnt) return;
    const int n0   = blockIdx.x * 64;
    const int tid  = threadIdx.x;
    const int lane = tid & 63;
    const int wid  = tid >> 6;
    const int wm   = wid >> 1, wn = wid & 1;

    __shared__ __hip_bfloat16 As[64 * 64];
    __shared__ __hip_bfloat16 Bs[64 * 64];
    __shared__ int s_tok[64];

    if (tid < 64) {
        int idx = m0 + tid;
        if (idx >= cnt) idx = cnt - 1;       // clamp: pad rows read a valid token
        s_tok[tid] = bucket[e * N_TOK + idx];
    }
    __syncthreads();

    // A staging: 2 global_load_lds(16B) per wave; instr i covers rows wid*16+i*8 .. +7
    const int rA0 = wid * 16 + (lane >> 3);
    const int rA1 = rA0 + 8;
    const int tok0 = s_tok[rA0];
    const int tok1 = s_tok[rA1];
    // pre-swizzled global source: phys slot (lane&7) holds logical slot (lane&7)^(row&7)
    const __hip_bfloat16* ga0 = A + (size_t)tok0 * K_TOT + (((lane & 7) ^ (rA0 & 7)) << 3);
    const __hip_bfloat16* ga1 = A + (size_t)tok1 * K_TOT + (((lane & 7) ^ (rA1 & 7)) << 3);
    char* lbA0 = (char*)As + (wid * 16) * 128;
    char* lbA1 = (char*)As + (wid * 16 + 8) * 128;

    // B staging: thread -> (k quad bkq, n group bc); loads 4 rows x 4 cols fp32,
    // converts to bf16, transposes 4x4, writes 4x ds_write_b64 into Bs[n][k] (swizzled)
    const int bc  = tid & 15;
    const int bkq = tid >> 4;
    const float* wbase = W + (size_t)e * K_TOT * N_TOT + (size_t)(bkq * 4) * N_TOT + n0 + bc * 4;

    f32x4_t acc[2][2];
#pragma unroll
    for (int f = 0; f < 2; ++f)
#pragma unroll
        for (int g = 0; g < 2; ++g) acc[f][g] = (f32x4_t){0.f, 0.f, 0.f, 0.f};

#pragma unroll 2
    for (int k0 = 0; k0 < K_TOT; k0 += 64) {
        // ---- stage A (async, per-lane gathered global source) ----
        gload16(ga0 + k0, lbA0);
        gload16(ga1 + k0, lbA1);
        // ---- stage B (reg-staged fp32 -> bf16, transposed) ----
        const float* wk = wbase + (size_t)k0 * N_TOT;
        const float4 v0 = *(const float4*)(wk + 0 * (size_t)N_TOT);
        const float4 v1 = *(const float4*)(wk + 1 * (size_t)N_TOT);
        const float4 v2 = *(const float4*)(wk + 2 * (size_t)N_TOT);
        const float4 v3 = *(const float4*)(wk + 3 * (size_t)N_TOT);
#pragma unroll
        for (int i = 0; i < 4; ++i) {
            const int n = bc * 4 + i;
            union { __hip_bfloat16 hh[4]; unsigned long long u; } pk;
            pk.hh[0] = __float2bfloat16(((const float*)&v0)[i]);
            pk.hh[1] = __float2bfloat16(((const float*)&v1)[i]);
            pk.hh[2] = __float2bfloat16(((const float*)&v2)[i]);
            pk.hh[3] = __float2bfloat16(((const float*)&v3)[i]);
            const int phys = n * 128 + (((bkq >> 1) ^ (n & 7)) << 4) + ((bkq & 1) << 3);
            *(unsigned long long*)((char*)Bs + phys) = pk.u;
        }
        __syncthreads();   // drains vmcnt (global_load_lds) + lgkm (ds_write)

        // ---- fragments + MFMA ----
#pragma unroll
        for (int kk = 0; kk < 2; ++kk) {
            uint4 af[2], bfr[2];
            const int ks = kk * 4 + (lane >> 4);
#pragma unroll
            for (int f = 0; f < 2; ++f) {
                const int r = wm * 32 + f * 16 + (lane & 15);
                af[f] = *(const uint4*)((const char*)As + r * 128 + ((ks ^ (r & 7)) << 4));
            }
#pragma unroll
            for (int g = 0; g < 2; ++g) {
                const int n = wn * 32 + g * 16 + (lane & 15);
                bfr[g] = *(const uint4*)((const char*)Bs + n * 128 + ((ks ^ (n & 7)) << 4));
            }
#pragma unroll
            for (int f = 0; f < 2; ++f)
#pragma unroll
                for (int g = 0; g < 2; ++g)
                    acc[f][g] = __builtin_amdgcn_mfma_f32_16x16x32_bf16(
                        __builtin_bit_cast(bf16x8_t, af[f]),
                        __builtin_bit_cast(bf16x8_t, bfr[g]),
                        acc[f][g], 0, 0, 0);
        }
        __syncthreads();   // protect LDS from next iteration's staging
    }

    // ---- epilogue: C/D layout col=lane&15, row=(lane>>4)*4+j ----
#pragma unroll
    for (int f = 0; f < 2; ++f) {
#pragma unroll
        for (int j = 0; j < 4; ++j) {
            const int rl = wm * 32 + f * 16 + (lane >> 4) * 4 + j;
            const bool ok = (m0 + rl) < cnt;
            const int tok = s_tok[rl];
#pragma unroll
            for (int g = 0; g < 2; ++g) {
                const int col = n0 + wn * 32 + g * 16 + (lane & 15);
                float v = acc[f][g][j] + bias[e * N_TOT + col];
                if (IS_FFN1) {
                    v = 0.5f * v * (1.0f + erff(v * 0.70710678118654752f));  // exact gelu
                    if (ok) hout[(size_t)tok * N_TOT + col] = __float2bfloat16(v);
                } else {
                    if (ok) yout[(size_t)tok * N_TOT + col] = v;
                }
            }
        }
    }
}

extern "C" void kernel_launch(void* const* d_in, const int* in_sizes, int n_in,
                              void* d_out, int out_size, void* d_ws, size_t ws_size,
                              hipStream_t stream) {
    const float* x  = (const float*)d_in[0];
    const float* Wg = (const float*)d_in[1];
    const float* bg = (const float*)d_in[2];
    const float* W1 = (const float*)d_in[3];
    const float* b1 = (const float*)d_in[4];
    const float* W2 = (const float*)d_in[5];
    const float* b2 = (const float*)d_in[6];
    float* out = (float*)d_out;

    char* ws = (char*)d_ws;
    int* counts = (int*)(ws);
    int* bucket = (int*)(ws + WS_BUCKET_OFF);
    __hip_bfloat16* xb = (__hip_bfloat16*)(ws + WS_XB_OFF);
    __hip_bfloat16* h  = (__hip_bfloat16*)(ws + WS_H_OFF);

    init_counts<<<dim3(1), dim3(64), 0, stream>>>(counts);
    router_kernel<<<dim3(N_TOK / 4), dim3(256), 0, stream>>>(x, Wg, bg, counts, bucket, xb);
    // FFN1: h[tok] = gelu(x[tok] @ W1[e] + b1[e]);  M<=4096 per expert, N=4096, K=1024
    ffn_gemm<D_MODEL, D_HIDDEN, true><<<dim3(D_HIDDEN / 64, N_TOK / 64, N_EXP), dim3(256), 0, stream>>>(
        xb, W1, b1, counts, bucket, h, nullptr);
    // FFN2: out[tok] = h[tok] @ W2[e] + b2[e];  N=1024, K=4096
    ffn_gemm<D_HIDDEN, D_MODEL, false><<<dim3(D_MODEL / 64, N_TOK / 64, N_EXP), dim3(256), 0, stream>>>(
        h, W2, b2, counts, bucket, nullptr, out);
}